// Round 4
// baseline (939.069 us; speedup 1.0000x reference)
//
#include <hip/hip_runtime.h>
#include <cstdint>
#include <cstddef>

// Problem constants
#define Bb   256
#define Tt   512
#define Ii   300
#define Hh   128
#define G4   512      // 4*H
#define KP   320      // K padded to multiple of 32 for MFMA

typedef _Float16 h2v   __attribute__((ext_vector_type(2)));
typedef _Float16 half8 __attribute__((ext_vector_type(8)));
typedef float    f32x4 __attribute__((ext_vector_type(4)));

typedef __attribute__((address_space(3))) unsigned int lds_uint;
typedef const __attribute__((address_space(1))) unsigned int glb_uint;

static __device__ __forceinline__ h2v as_h2(unsigned int u){ union{unsigned int u; h2v h;} c; c.u=u; return c.h; }
static __device__ __forceinline__ unsigned int as_u32(h2v h){ union{unsigned int u; h2v h;} c; c.h=h; return c.u; }
static __device__ __forceinline__ half8 as_half8(uint4 u){ union{uint4 u; half8 h;} c; c.u=u; return c.h; }

// ---------------- conversion: x fp32 [131072,300] -> f16 padded [131072,320] ----------------
__global__ __launch_bounds__(256) void conv_x(const float* __restrict__ x, unsigned int* __restrict__ x16){
  int idx = blockIdx.x*256 + threadIdx.x;      // half2 index; total 131072*160, grid exact
  int r   = idx / 160;
  int kk2 = idx - r*160;
  int kk  = kk2*2;
  const float* xr = x + (size_t)r*Ii;
  float v0 = (kk   < Ii) ? xr[kk]   : 0.f;
  float v1 = (kk+1 < Ii) ? xr[kk+1] : 0.f;
  h2v h; h[0] = (_Float16)v0; h[1] = (_Float16)v1;
  x16[idx] = as_u32(h);
}

// ---------------- conversion: W_ih -> f16 padded, W_hh -> packed half2 [512][64], bias sum ----------------
__global__ __launch_bounds__(256) void conv_small(const float* __restrict__ Wih, const float* __restrict__ Whh,
      const float* __restrict__ bih, const float* __restrict__ bhh,
      unsigned int* __restrict__ W16, unsigned int* __restrict__ Whh2, float* __restrict__ bias){
  int idx = blockIdx.x*256 + threadIdx.x;
  if (idx < G4*160){
    int r = idx/160, kk2 = idx - r*160, kk = kk2*2;
    const float* wr = Wih + (size_t)r*Ii;
    float v0 = (kk   < Ii) ? wr[kk]   : 0.f;
    float v1 = (kk+1 < Ii) ? wr[kk+1] : 0.f;
    h2v h; h[0]=(_Float16)v0; h[1]=(_Float16)v1;
    W16[idx] = as_u32(h);
  } else if (idx < G4*160 + G4*64){
    int t = idx - G4*160; int j = t>>6, kk = t&63;
    float v0 = Whh[j*Hh + kk*2], v1 = Whh[j*Hh + kk*2 + 1];
    h2v h; h[0]=(_Float16)v0; h[1]=(_Float16)v1;
    Whh2[t] = as_u32(h);
  } else if (idx < G4*160 + G4*64 + G4){
    int d = idx - (G4*160 + G4*64);
    bias[d] = bih[d] + bhh[d];
  }
}

// ---------------- phase 1: xg[131072,512] = A16 @ W16^T + bias, f16 MFMA ----------------
__global__ __launch_bounds__(256,2) void gemm16(const _Float16* __restrict__ A, const _Float16* __restrict__ Bm,
       const float* __restrict__ bias, float* __restrict__ C){
  __shared__ __align__(16) _Float16 As[128*32];
  __shared__ __align__(16) _Float16 Bs[128*32];
  int tid = threadIdx.x;
  int w = tid>>6, lane = tid&63;
  int bm = blockIdx.x*128, bn = blockIdx.y*128;
  f32x4 acc[2][8];
  #pragma unroll
  for (int i=0;i<2;i++)
    #pragma unroll
    for (int j=0;j<8;j++) acc[i][j] = (f32x4){0.f,0.f,0.f,0.f};

  int L0 = w*128 + lane, L1 = L0 + 64;
  int r0 = L0>>2, c0 = (L0&3) ^ (r0&3);
  int r1 = L1>>2, c1 = (L1&3) ^ (r1&3);
  const _Float16* gA0 = A  + (size_t)(bm+r0)*KP + c0*8;
  const _Float16* gA1 = A  + (size_t)(bm+r1)*KP + c1*8;
  const _Float16* gB0 = Bm + (size_t)(bn+r0)*KP + c0*8;
  const _Float16* gB1 = Bm + (size_t)(bn+r1)*KP + c1*8;

  int q = lane>>4, mr = lane&15;
  int m0 = w*32;
  int ra0 = m0+mr, ra1 = m0+16+mr;
  int oa0 = ra0*32 + ((q ^ (ra0&3))*8);
  int oa1 = ra1*32 + ((q ^ (ra1&3))*8);
  int ob[8];
  #pragma unroll
  for (int j=0;j<8;j++){ int rb = j*16+mr; ob[j] = rb*32 + ((q ^ (rb&3))*8); }

  for (int kt=0; kt<KP/32; ++kt){
    __syncthreads();
    __builtin_amdgcn_global_load_lds((glb_uint*)gA0, (lds_uint*)&As[w*1024      ], 16, 0, 0);
    __builtin_amdgcn_global_load_lds((glb_uint*)gA1, (lds_uint*)&As[w*1024 + 512], 16, 0, 0);
    __builtin_amdgcn_global_load_lds((glb_uint*)gB0, (lds_uint*)&Bs[w*1024      ], 16, 0, 0);
    __builtin_amdgcn_global_load_lds((glb_uint*)gB1, (lds_uint*)&Bs[w*1024 + 512], 16, 0, 0);
    gA0 += 32; gA1 += 32; gB0 += 32; gB1 += 32;
    __syncthreads();
    half8 af0 = *(const half8*)&As[oa0];
    half8 af1 = *(const half8*)&As[oa1];
    #pragma unroll
    for (int j=0;j<8;j++){
      half8 bf = *(const half8*)&Bs[ob[j]];
      acc[0][j] = __builtin_amdgcn_mfma_f32_16x16x32_f16(af0, bf, acc[0][j], 0,0,0);
      acc[1][j] = __builtin_amdgcn_mfma_f32_16x16x32_f16(af1, bf, acc[1][j], 0,0,0);
    }
  }
  #pragma unroll
  for (int j=0;j<8;j++){
    int gc = bn + j*16 + mr;
    float bv = bias[gc];
    #pragma unroll
    for (int i=0;i<2;i++){
      int gr0 = bm + w*32 + i*16 + q*4;
      #pragma unroll
      for (int reg=0; reg<4; ++reg)
        C[(size_t)(gr0+reg)*G4 + gc] = acc[i][j][reg] + bv;
    }
  }
}

// ---------------- phase 2: recurrence via MFMA, one block per batch chain ----------------
// 512 threads = 8 waves. Wave w holds B-frags (W_hh gate-cols [64w,64w+64), 16 frags = 64
// regs, VGPR or AGPR — MFMA reads either directly, so the allocator can't hurt us).
// h (128 f16) lives in LDS row 0 of the A-tile; only mr==0 lanes load real A-frag data
// (M-rows 1..15 are zero, their C rows are ignored). Gates go through LDS once per step;
// 128 act lanes (lane<16 of every wave) do sigmoid/tanh + c/h update.
__global__ __launch_bounds__(512,2) void lstm_rec(const float* __restrict__ xg, const unsigned int* __restrict__ Whh2,
     const float* __restrict__ fcw, const float* __restrict__ fcb, float* __restrict__ out){
  int tid = threadIdx.x;
  int b = blockIdx.x;
  int w = tid>>6, lane = tid&63;
  int q = lane>>4, mr = lane&15;
  int nb = w*64;

  // B-fragments: bf[jn][kt] = W_hh rows (gate-cols) nb+jn*16+mr, k-halves kt*32+q*8..+8
  uint4 bf[4][4];
  #pragma unroll
  for (int jn=0; jn<4; ++jn)
    #pragma unroll
    for (int kt=0; kt<4; ++kt)
      bf[jn][kt] = *(const uint4*)&Whh2[(size_t)(nb + jn*16 + mr)*64 + kt*16 + q*4];

  __shared__ __align__(16) _Float16 hA[128];   // h in f16, A-tile row 0
  __shared__ float gsh[512];                   // gate pre-acts (h-part)
  __shared__ float red[8];
  if (tid < 64) ((unsigned int*)hA)[tid] = 0;

  bool act = (lane < 16);
  int d = nb/4 + mr;                           // w*16 + mr, 0..127
  const float* xrow = xg + (size_t)b * (Tt*G4);
  float xc0=0.f, xc1=0.f, xc2=0.f, xc3=0.f;
  if (act){ xc0 = xrow[d]; xc1 = xrow[128+d]; xc2 = xrow[256+d]; xc3 = xrow[384+d]; }
  float creg = 0.f, hreg = 0.f;
  __syncthreads();

  for (int t=0; t<Tt; ++t){
    // prefetch next step's input pre-acts (consumed after the barrier)
    float xn0=0.f, xn1=0.f, xn2=0.f, xn3=0.f;
    {
      int tn = (t+1 < Tt) ? t+1 : t;
      const float* xr = xrow + (size_t)tn*G4;
      if (act){ xn0 = xr[d]; xn1 = xr[128+d]; xn2 = xr[256+d]; xn3 = xr[384+d]; }
    }
    // A-fragments: only mr==0 lanes carry row 0 (= h); other rows zero
    half8 a[4];
    #pragma unroll
    for (int kt=0; kt<4; ++kt){
      half8 v = (half8){0,0,0,0,0,0,0,0};
      if (mr == 0) v = *(const half8*)&hA[kt*32 + q*8];
      a[kt] = v;
    }
    // MFMA: C[row=q*4+reg][col=jn*16+mr]; row 0 (q==0, reg 0) is the real batch row
    #pragma unroll
    for (int jn=0; jn<4; ++jn){
      f32x4 acc = (f32x4){0.f,0.f,0.f,0.f};
      #pragma unroll
      for (int kt=0; kt<4; ++kt)
        acc = __builtin_amdgcn_mfma_f32_16x16x32_f16(a[kt], as_half8(bf[jn][kt]), acc, 0,0,0);
      if (q == 0) gsh[nb + jn*16 + mr] = acc[0];
    }
    __syncthreads();
    if (act){
      float ai = gsh[      d] + xc0;
      float af = gsh[128 + d] + xc1;
      float ag = gsh[256 + d] + xc2;
      float ao = gsh[384 + d] + xc3;
      float i_ = 1.f/(1.f+__expf(-ai));
      float f_ = 1.f/(1.f+__expf(-af));
      float eg = __expf(2.f*ag); float g_ = 1.f - 2.f/(eg+1.f);
      float o_ = 1.f/(1.f+__expf(-ao));
      creg = f_*creg + i_*g_;
      float ec = __expf(2.f*creg); float tc = 1.f - 2.f/(ec+1.f);
      hreg = o_*tc;
      hA[d] = (_Float16)hreg;
      xc0 = xn0; xc1 = xn1; xc2 = xn2; xc3 = xn3;
    }
    __syncthreads();
  }

  // fused FC: out[b] = sum_d h_d * fcw[d] + fcb
  float p = act ? hreg * fcw[d] : 0.f;
  p += __shfl_xor(p, 1, 64);
  p += __shfl_xor(p, 2, 64);
  p += __shfl_xor(p, 4, 64);
  p += __shfl_xor(p, 8, 64);
  if (lane == 0) red[w] = p;
  __syncthreads();
  if (tid == 0){
    float s = fcb[0];
    #pragma unroll
    for (int k=0;k<8;k++) s += red[k];
    out[b] = s;
  }
}

extern "C" void kernel_launch(void* const* d_in, const int* in_sizes, int n_in,
                              void* d_out, int out_size, void* d_ws, size_t ws_size,
                              hipStream_t stream){
  const float* x   = (const float*)d_in[0];
  const float* Wih = (const float*)d_in[1];
  const float* Whh = (const float*)d_in[2];
  const float* bih = (const float*)d_in[3];
  const float* bhh = (const float*)d_in[4];
  const float* fcw = (const float*)d_in[5];
  const float* fcb = (const float*)d_in[6];
  float* out = (float*)d_out;
  char* ws = (char*)d_ws;

  unsigned int* x16   = (unsigned int*)(ws);
  unsigned int* W16   = (unsigned int*)(ws + 83886080);
  unsigned int* Whh2w = (unsigned int*)(ws + 84213760);
  float*        bias  = (float*)      (ws + 84344832);
  float*        xg    = (float*)      (ws + 84346880);

  hipLaunchKernelGGL(conv_x,     dim3(81920),  dim3(256), 0, stream, x, x16);
  hipLaunchKernelGGL(conv_small, dim3(450),    dim3(256), 0, stream, Wih, Whh, bih, bhh, W16, Whh2w, bias);
  hipLaunchKernelGGL(gemm16,     dim3(1024,4), dim3(256), 0, stream,
                     (const _Float16*)x16, (const _Float16*)W16, bias, xg);
  hipLaunchKernelGGL(lstm_rec,   dim3(256),    dim3(512), 0, stream, xg, Whh2w, fcw, fcb, out);
}

// Round 5
// 723.743 us; speedup vs baseline: 1.2975x; 1.2975x over previous
//
#include <hip/hip_runtime.h>
#include <cstdint>
#include <cstddef>

// Problem constants
#define Bb   256
#define Tt   512
#define Ii   300
#define Hh   128
#define G4   512      // 4*H
#define KP   320      // K padded to multiple of 32 for MFMA

typedef _Float16 h2v   __attribute__((ext_vector_type(2)));
typedef _Float16 half8 __attribute__((ext_vector_type(8)));
typedef float    f32x4 __attribute__((ext_vector_type(4)));

typedef __attribute__((address_space(3))) unsigned int lds_uint;
typedef const __attribute__((address_space(1))) unsigned int glb_uint;

static __device__ __forceinline__ h2v as_h2(unsigned int u){ union{unsigned int u; h2v h;} c; c.u=u; return c.h; }
static __device__ __forceinline__ unsigned int as_u32(h2v h){ union{unsigned int u; h2v h;} c; c.h=h; return c.u; }

#if __has_builtin(__builtin_amdgcn_fdot2)
#define FDOT2(a,b,c) __builtin_amdgcn_fdot2((a),(b),(c),false)
#else
static __device__ __forceinline__ float FDOT2(h2v a, h2v b, float c){
  return c + (float)a[0]*(float)b[0] + (float)a[1]*(float)b[1];
}
#endif

// ---------------- conversion: x fp32 [131072,300] -> f16 padded [131072,320] ----------------
__global__ __launch_bounds__(256) void conv_x(const float* __restrict__ x, unsigned int* __restrict__ x16){
  int idx = blockIdx.x*256 + threadIdx.x;      // half2 index; total 131072*160, grid exact
  int r   = idx / 160;
  int kk2 = idx - r*160;
  int kk  = kk2*2;
  const float* xr = x + (size_t)r*Ii;
  float v0 = (kk   < Ii) ? xr[kk]   : 0.f;
  float v1 = (kk+1 < Ii) ? xr[kk+1] : 0.f;
  h2v h; h[0] = (_Float16)v0; h[1] = (_Float16)v1;
  x16[idx] = as_u32(h);
}

// ---------------- conversion: W_ih -> f16 padded, W_hh -> packed half2 [512][64], bias sum ----------------
__global__ __launch_bounds__(256) void conv_small(const float* __restrict__ Wih, const float* __restrict__ Whh,
      const float* __restrict__ bih, const float* __restrict__ bhh,
      unsigned int* __restrict__ W16, unsigned int* __restrict__ Whh2, float* __restrict__ bias){
  int idx = blockIdx.x*256 + threadIdx.x;
  if (idx < G4*160){
    int r = idx/160, kk2 = idx - r*160, kk = kk2*2;
    const float* wr = Wih + (size_t)r*Ii;
    float v0 = (kk   < Ii) ? wr[kk]   : 0.f;
    float v1 = (kk+1 < Ii) ? wr[kk+1] : 0.f;
    h2v h; h[0]=(_Float16)v0; h[1]=(_Float16)v1;
    W16[idx] = as_u32(h);
  } else if (idx < G4*160 + G4*64){
    int t = idx - G4*160; int j = t>>6, kk = t&63;
    float v0 = Whh[j*Hh + kk*2], v1 = Whh[j*Hh + kk*2 + 1];
    h2v h; h[0]=(_Float16)v0; h[1]=(_Float16)v1;
    Whh2[t] = as_u32(h);
  } else if (idx < G4*160 + G4*64 + G4){
    int d = idx - (G4*160 + G4*64);
    bias[d] = bih[d] + bhh[d];
  }
}

// ---------------- phase 1: xg[131072,512] = A16 @ W16^T + bias, f16 MFMA ----------------
__global__ __launch_bounds__(256,2) void gemm16(const _Float16* __restrict__ A, const _Float16* __restrict__ Bm,
       const float* __restrict__ bias, float* __restrict__ C){
  __shared__ __align__(16) _Float16 As[128*32];
  __shared__ __align__(16) _Float16 Bs[128*32];
  int tid = threadIdx.x;
  int w = tid>>6, lane = tid&63;
  int bm = blockIdx.x*128, bn = blockIdx.y*128;
  f32x4 acc[2][8];
  #pragma unroll
  for (int i=0;i<2;i++)
    #pragma unroll
    for (int j=0;j<8;j++) acc[i][j] = (f32x4){0.f,0.f,0.f,0.f};

  int L0 = w*128 + lane, L1 = L0 + 64;
  int r0 = L0>>2, c0 = (L0&3) ^ (r0&3);
  int r1 = L1>>2, c1 = (L1&3) ^ (r1&3);
  const _Float16* gA0 = A  + (size_t)(bm+r0)*KP + c0*8;
  const _Float16* gA1 = A  + (size_t)(bm+r1)*KP + c1*8;
  const _Float16* gB0 = Bm + (size_t)(bn+r0)*KP + c0*8;
  const _Float16* gB1 = Bm + (size_t)(bn+r1)*KP + c1*8;

  int q = lane>>4, mr = lane&15;
  int m0 = w*32;
  int ra0 = m0+mr, ra1 = m0+16+mr;
  int oa0 = ra0*32 + ((q ^ (ra0&3))*8);
  int oa1 = ra1*32 + ((q ^ (ra1&3))*8);
  int ob[8];
  #pragma unroll
  for (int j=0;j<8;j++){ int rb = j*16+mr; ob[j] = rb*32 + ((q ^ (rb&3))*8); }

  for (int kt=0; kt<KP/32; ++kt){
    __syncthreads();
    __builtin_amdgcn_global_load_lds((glb_uint*)gA0, (lds_uint*)&As[w*1024      ], 16, 0, 0);
    __builtin_amdgcn_global_load_lds((glb_uint*)gA1, (lds_uint*)&As[w*1024 + 512], 16, 0, 0);
    __builtin_amdgcn_global_load_lds((glb_uint*)gB0, (lds_uint*)&Bs[w*1024      ], 16, 0, 0);
    __builtin_amdgcn_global_load_lds((glb_uint*)gB1, (lds_uint*)&Bs[w*1024 + 512], 16, 0, 0);
    gA0 += 32; gA1 += 32; gB0 += 32; gB1 += 32;
    __syncthreads();
    half8 af0 = *(const half8*)&As[oa0];
    half8 af1 = *(const half8*)&As[oa1];
    #pragma unroll
    for (int j=0;j<8;j++){
      half8 bf = *(const half8*)&Bs[ob[j]];
      acc[0][j] = __builtin_amdgcn_mfma_f32_16x16x32_f16(af0, bf, acc[0][j], 0,0,0);
      acc[1][j] = __builtin_amdgcn_mfma_f32_16x16x32_f16(af1, bf, acc[1][j], 0,0,0);
    }
  }
  #pragma unroll
  for (int j=0;j<8;j++){
    int gc = bn + j*16 + mr;
    float bv = bias[gc];
    #pragma unroll
    for (int i=0;i<2;i++){
      int gr0 = bm + w*32 + i*16 + q*4;
      #pragma unroll
      for (int reg=0; reg<4; ++reg)
        C[(size_t)(gr0+reg)*G4 + gc] = acc[i][j][reg] + bv;
    }
  }
}

// ---------------- phase 2: recurrence, one block per batch chain ----------------
// 512 threads = 8 waves (2/SIMD). Thread t owns gate row t: 64 half2 weights, 64 fdot2/step.
// xg staged in 16-step (32 KB) double-buffered LDS chunks via async global_load_lds;
// the per-step barrier's vmcnt(0) drain guarantees chunk completion (issued 16 steps early).
// Gates staged as gsh[g*128+d] (conflict-free); c/h update replicated across the 4 gate
// replicas of each d (no idle-wave specialization, no float4 conflicts).
__global__ __launch_bounds__(512,2) void lstm_rec(const float* __restrict__ xg, const unsigned int* __restrict__ Whh2,
     const float* __restrict__ fcw, const float* __restrict__ fcb, float* __restrict__ out){
  int tid = threadIdx.x;           // 0..511 ; gate row r = tid ; g = tid>>7 (wave-uniform)
  int b = blockIdx.x;
  int d = tid & 127;
  h2v w[64];
  #pragma unroll
  for (int k=0; k<64; ++k) w[k] = as_h2(Whh2[tid*64 + k]);

  __shared__ __align__(16) unsigned short hsh[128];
  __shared__ float gsh[512];                 // [g*128 + d]
  __shared__ __align__(16) float xbuf[2][16*G4];  // 2 x 32 KB chunks
  if (tid < 64) ((unsigned int*)hsh)[tid] = 0;

  const float* xrow = xg + (size_t)b * (Tt*G4);
  int wv = tid >> 6, lane = tid & 63;

  // stage chunk c (steps [16c,16c+16)) into xbuf[c&1]
  auto stage = [&](int c){
    const float* src = xrow + (size_t)c*16*G4;
    float* dst = xbuf[c & 1];
    #pragma unroll
    for (int i=0; i<4; ++i){
      int off = i*2048 + wv*256;             // floats, wave-uniform
      __builtin_amdgcn_global_load_lds((glb_uint*)(src + off + lane*4),
                                       (lds_uint*)(dst + off), 16, 0, 0);
    }
  };

  stage(0);
  float creg = 0.f, hreg = 0.f;
  __syncthreads();                            // drains stage(0) too

  for (int t=0; t<Tt; ++t){
    if ((t & 15) == 0){
      int nc = (t >> 4) + 1;
      if (nc < Tt/16) stage(nc);
    }
    float xv = xbuf[(t >> 4) & 1][(t & 15)*G4 + tid];   // ds_read_b32, hidden under dot
    float a0 = 0.f, a1 = 0.f;
    const uint4* hv = (const uint4*)hsh;
    #pragma unroll
    for (int kq=0; kq<8; ++kq){
      uint4 hq0 = hv[kq*2], hq1 = hv[kq*2+1];
      a0 = FDOT2(as_h2(hq0.x), w[kq*8+0], a0); a1 = FDOT2(as_h2(hq0.y), w[kq*8+1], a1);
      a0 = FDOT2(as_h2(hq0.z), w[kq*8+2], a0); a1 = FDOT2(as_h2(hq0.w), w[kq*8+3], a1);
      a0 = FDOT2(as_h2(hq1.x), w[kq*8+4], a0); a1 = FDOT2(as_h2(hq1.y), w[kq*8+5], a1);
      a0 = FDOT2(as_h2(hq1.z), w[kq*8+6], a0); a1 = FDOT2(as_h2(hq1.w), w[kq*8+7], a1);
    }
    float a = a0 + a1 + xv;
    float act;
    if ((tid >> 7) == 2){ float e = __expf(2.f*a); act = 1.f - 2.f/(e+1.f); }  // tanh (gate g)
    else                { act = 1.f/(1.f+__expf(-a)); }                         // sigmoid
    gsh[tid] = act;
    __syncthreads();
    float gi = gsh[d], gf = gsh[128+d], gg = gsh[256+d], go = gsh[384+d];
    creg = gf*creg + gi*gg;
    float ec = __expf(2.f*creg); float tc = 1.f - 2.f/(ec+1.f);
    hreg = go*tc;
    if (tid < 128){
      union{ _Float16 f; unsigned short u; } cv; cv.f = (_Float16)hreg;
      hsh[tid] = cv.u;
    }
    __syncthreads();
  }

  // fused FC: out[b] = sum_d h_d * fcw[d] + fcb
  if (tid < 128) gsh[tid] = hreg * fcw[tid];
  __syncthreads();
  if (tid < 64){
    float s = gsh[tid] + gsh[tid+64];
    #pragma unroll
    for (int st=32; st>=1; st>>=1) s += __shfl_down(s, st, 64);
    if (tid == 0) out[b] = s + fcb[0];
  }
}

extern "C" void kernel_launch(void* const* d_in, const int* in_sizes, int n_in,
                              void* d_out, int out_size, void* d_ws, size_t ws_size,
                              hipStream_t stream){
  const float* x   = (const float*)d_in[0];
  const float* Wih = (const float*)d_in[1];
  const float* Whh = (const float*)d_in[2];
  const float* bih = (const float*)d_in[3];
  const float* bhh = (const float*)d_in[4];
  const float* fcw = (const float*)d_in[5];
  const float* fcb = (const float*)d_in[6];
  float* out = (float*)d_out;
  char* ws = (char*)d_ws;

  unsigned int* x16   = (unsigned int*)(ws);
  unsigned int* W16   = (unsigned int*)(ws + 83886080);
  unsigned int* Whh2w = (unsigned int*)(ws + 84213760);
  float*        bias  = (float*)      (ws + 84344832);
  float*        xg    = (float*)      (ws + 84346880);

  hipLaunchKernelGGL(conv_x,     dim3(81920),  dim3(256), 0, stream, x, x16);
  hipLaunchKernelGGL(conv_small, dim3(450),    dim3(256), 0, stream, Wih, Whh, bih, bhh, W16, Whh2w, bias);
  hipLaunchKernelGGL(gemm16,     dim3(1024,4), dim3(256), 0, stream,
                     (const _Float16*)x16, (const _Float16*)W16, bias, xg);
  hipLaunchKernelGGL(lstm_rec,   dim3(256),    dim3(512), 0, stream, xg, Whh2w, fcw, fcb, out);
}